// Round 7
// baseline (424.604 us; speedup 1.0000x reference)
//
#include <hip/hip_runtime.h>
#include <math.h>

// Full-fidelity emulation of the reference as run by jax-rocm EAGERLY on this
// GPU (x64 on): all f64 transcendentals are __ocml_*_f64 == this kernel's
// exp()/log(). Both stages are inexact because jax lowers exp2(z) ->
// exp(RN(z*RN(ln2))) -- reproduced bit-for-bit.
//
// R7 changes (numerics bit-identical, VGPR-cliff-targeted):
//  * R6 post-mortem: __launch_bounds__(512,6) capped VGPR at ~85 -- ABOVE the
//    measured 64-VGPR occupancy cliff (waves/CU halve at 64/128/256), so the
//    kernel stayed at 4 waves/SIMD and the TLP lever was never pulled (-0.4us
//    noise). This round: __launch_bounds__(512, 8) -> hard 64-VGPR cap -> 8
//    waves/SIMD eligible.
//  * Load buffer split into two 4-chunk batches A[4]/B[4] so peak register
//    pressure fits 64 without spills: A issued before the table phase, B after
//    (B's latency hides under pack-A via counted vmcnt); full 8KB/wave MLP
//    retained.
//  * Stores revert to NORMAL (NT dropped): the 6.29 TB/s copy ubench and the
//    6.5 TB/s harness fills both use normal stores; NT-store may bypass
//    write-combining. Loads keep NT (input is never re-read).
//  * Wave-local dataflow unchanged from R4/R6: value->lane map v = vwave +
//    (lane&7)*8 + (lane>>3); pack keeps own word (select i==lane&7); store
//    word via one __shfl from lane (lane&56)+i. No LDS data path.
//  * Encode shortcuts unchanged (absmax==0 four times):
//    - mantissa!=0 -> floor(log(a)/LN2) == E exactly (emu err ~1e-13 vs
//      1.7e-7 distance to integer); subnormal -> clip == -126; mantissa==0
//      (exact pow2) -> rare verbatim ocml log() path.
//    - mant = M + e, |e| <~ 1e-8: for sc > ctz(M), floor(mant*Lm[sc]) ==
//      M>>sc exactly -> parity is bit sc of M; only sc <= ctz(M) (incl. the
//      pow2 M=0 "W-1 garbage" case) runs the original f64 mul+floor step.

#define LN2C 0x1.62e42fefa39efp-1  // RN(ln2), XLA's folded log(2)

typedef unsigned int u32x4 __attribute__((ext_vector_type(4)));

__global__ __launch_bounds__(512, 8) void spike_gelu_kernel(
    const u32x4* __restrict__ in, u32x4* __restrict__ out, int n_vals) {
#pragma clang fp contract(off)
  const double LN2 = LN2C;
  // Tables (exact ocml-call replicas of the reference's constant arrays):
  __shared__ double Wdec[8];     // decode exponent weights exp2emu(7..0)
  __shared__ double Lms[23];     // ladder scales exp2emu(0..-22)
  __shared__ double E1t[256];    // ordered Wdec sum -> exp((e_c-127)*LN2)
  __shared__ double Vdec[23];    // decode fraction weights exp2emu(-1..-23)
  __shared__ double P2t[254];    // encode exp(-e0*LN2), e0 in [-126,127]
  __shared__ uint32_t etab[256]; // 8-step exponent floor-ladder per eb

  const int tid = threadIdx.x;
  const int lane = tid & 63;
  const int wid = tid >> 6;  // 0..7
  const int n_chunks = n_vals * 8;

  // Wave owns 64 values; its 512 chunks start at cbase.
  const int vwave = blockIdx.x * 512 + wid * 64;
  const int cbase = vwave * 8 + lane;

  // ---- batch-0 loads (4 x 16B in flight under the table build) ------------
  u32x4 A[4];
#pragma unroll
  for (int i = 0; i < 4; ++i) {
    int g = cbase + i * 64;
    u32x4 b = {0u, 0u, 0u, 0u};
    if (g < n_chunks) b = __builtin_nontemporal_load(&in[g]);
    A[i] = b;
  }

  // ---- table stage 1 ------------------------------------------------------
  if (tid < 8) Wdec[tid] = exp((double)(7 - tid) * LN2);
  if (tid >= 31 && tid < 54) Lms[tid - 31] = exp((double)(31 - tid) * LN2);
  __syncthreads();
  // ---- table stage 2 (reference op order; split across all 8 waves) -------
  if (tid == 0) {
    E1t[0] = exp(-126.0 * LN2);  // subnormal-branch scale (e_c==0)
  } else if (tid < 256) {
    double e_c = 0.0;
#pragma unroll
    for (int j = 0; j < 8; ++j)   // ascending-j einsum accumulation, verbatim
      if ((tid >> (7 - j)) & 1) e_c = e_c + Wdec[j];
    E1t[tid] = exp((e_c - 127.0) * LN2);
  }
  if (tid < 23) Vdec[tid] = exp((double)(-1 - tid) * LN2);
  if (tid < 254) P2t[tid] = exp((double)(126 - tid) * LN2);  // exp(-e0*LN2)
  if (tid >= 256) {  // upper 4 waves: exponent-bit ladder, original formula
    const int tt = tid - 256;
    if (tt >= 1 && tt < 255) {
      double eb = (double)tt;
      uint32_t r = 0;
#pragma unroll
      for (int sc = 7; sc >= 0; --sc) {
        double f = floor(eb * Lms[sc]);
        double md = f - 2.0 * floor(0.5 * f);
        r |= ((uint32_t)md) << (23 + sc);
      }
      etab[tt] = r;
    } else {
      etab[tt] = 0u;  // hygiene, never read
    }
  }
  __syncthreads();  // tables ready; no further block-wide coupling

  // ---- batch-1 loads (in flight under pack of batch 0) --------------------
  u32x4 Bb[4];
#pragma unroll
  for (int i = 0; i < 4; ++i) {
    int g = cbase + (i + 4) * 64;
    u32x4 b = {0u, 0u, 0u, 0u};
    if (g < n_chunks) b = __builtin_nontemporal_load(&in[g]);
    Bb[i] = b;
  }

  // ---- pack: wave-local bit transpose -------------------------------------
  // Chunk cbase+i*64+lane holds value vwave+i*8+(lane>>3), nibble pos lane&7.
  // After the 3 xor-ors all 8 lanes of a group hold that value's word; lane
  // keeps its own value (v = vwave + (lane&7)*8 + (lane>>3)) at i == lane&7.
  const int nibshift = 28 - 4 * (lane & 7);
  const int keep = lane & 7;
  uint32_t w0 = 0u;
#pragma unroll
  for (int i = 0; i < 4; ++i) {
    u32x4 b = A[i];
    uint32_t p = (((((b.x >> 23) & 1u) << 3) | (((b.y >> 23) & 1u) << 2) |
                   (((b.z >> 23) & 1u) << 1) | ((b.w >> 23) & 1u)))
                 << nibshift;
    p |= __shfl_xor(p, 1);
    p |= __shfl_xor(p, 2);
    p |= __shfl_xor(p, 4);
    if (keep == i) w0 = p;
  }
#pragma unroll
  for (int i = 0; i < 4; ++i) {
    u32x4 b = Bb[i];
    uint32_t p = (((((b.x >> 23) & 1u) << 3) | (((b.y >> 23) & 1u) << 2) |
                   (((b.z >> 23) & 1u) << 1) | ((b.w >> 23) & 1u)))
                 << nibshift;
    p |= __shfl_xor(p, 1);
    p |= __shfl_xor(p, 2);
    p |= __shfl_xor(p, 4);
    if (keep == (i + 4)) w0 = p;
  }

  // ---- per-value chain (bit-identical to R4/R6) ---------------------------
  const int v0 = vwave + (lane & 7) * 8 + (lane >> 3);
  const bool ok0 = v0 < n_vals;

  // DECODE
  double f0 = 0.0;
#pragma unroll
  for (int j = 0; j < 23; ++j)
    if ((w0 >> (22 - j)) & 1u) f0 = f0 + Vdec[j];
  uint32_t ei0 = (w0 >> 23) & 0xFFu;
  double sg0 = (w0 >> 31) ? -1.0 : 1.0;
  double fa0 = ei0 ? (1.0 + f0) : f0;
  double x0 = (sg0 * E1t[ei0]) * fa0;

  // f64 GELU, exp-form logistic, ocml exp
  double t0 = 1.702 * x0;
  double e0v = exp(-t0);
  double s0 = 1.0 / (1.0 + e0v);
  double y0 = x0 * s0;
  float yf0 = (float)y0;   // astype(float32): RN
  double yd0 = (double)yf0;

  // ENCODE
  double a0 = fabs(yd0);
  uint32_t yb0 = __float_as_uint(yf0);
  uint32_t Ef0 = (yb0 >> 23) & 0xFFu;
  uint32_t mbf0 = yb0 & 0x7FFFFFu;
  int e00 = (Ef0 == 0u) ? -126 : (int)Ef0 - 127;
  bool pw0 = ok0 && (a0 > 0.0) && (Ef0 != 0u) && (mbf0 == 0u);
  if (__builtin_expect(pw0, 0)) {  // exact pow2: ocml log boundary, verbatim
    double e0 = floor(log(a0) / LN2);
    e00 = (int)fmin(fmax(e0, -126.0), 127.0);
  }
  double p20 = P2t[e00 + 126];
  double m10 = a0 * p20;               // RN: may be W' +- eps
  double mant0 = (m10 - 1.0) * 8388608.0;  // Sterbenz-exact, exact scale
  int M0 = (int)rint(mant0);
  uint32_t mb0 = ((uint32_t)M0) & 0x7FFFFFu;
  int T0 = M0 ? __builtin_ctz((uint32_t)M0) : 23;
  int L0 = T0 < 22 ? T0 : 22;
  for (int sc = 0; sc <= L0; ++sc) {   // boundary scs: original f64 math
    double f = floor(mant0 * Lms[sc]);
    mb0 = (mb0 & ~(1u << sc)) | (((uint32_t)(((int)f) & 1)) << sc);
  }
  uint32_t ob0 = (yb0 & 0x80000000u) | etab[e00 + 127] | mb0;
  ob0 = (ok0 && a0 > 0.0) ? ob0 : 0u;

  // ---- store: wave-local pulse expansion (normal stores) ------------------
  // Chunk cbase+i*64 needs value vwave+i*8+(lane>>3), held at lane
  // (lane&56)+i under the map above. Issue all 8 bpermutes, then expand.
  uint32_t wv[8];
#pragma unroll
  for (int i = 0; i < 8; ++i) wv[i] = __shfl(ob0, (lane & 56) + i);
  const int base = 31 - 4 * (lane & 7);
#pragma unroll
  for (int i = 0; i < 8; ++i) {
    int g = cbase + i * 64;
    if (g < n_chunks) {
      uint32_t wa = wv[i];
      u32x4 o;
      o.x = ((wa >> base) & 1u) * 0x3F800000u;
      o.y = ((wa >> (base - 1)) & 1u) * 0x3F800000u;
      o.z = ((wa >> (base - 2)) & 1u) * 0x3F800000u;
      o.w = ((wa >> (base - 3)) & 1u) * 0x3F800000u;
      out[g] = o;
    }
  }
}

extern "C" void kernel_launch(void* const* d_in, const int* in_sizes, int n_in,
                              void* d_out, int out_size, void* d_ws, size_t ws_size,
                              hipStream_t stream) {
  int n_vals = in_sizes[0] / 32;
  int grid = (n_vals + 511) / 512;
  spike_gelu_kernel<<<grid, 512, 0, stream>>>(
      (const u32x4*)d_in[0], (u32x4*)d_out, n_vals);
}

// Round 8
// 418.205 us; speedup vs baseline: 1.0153x; 1.0153x over previous
//
#include <hip/hip_runtime.h>
#include <math.h>

// Full-fidelity emulation of the reference as run by jax-rocm EAGERLY on this
// GPU (x64 on): all f64 transcendentals are __ocml_*_f64 == this kernel's
// exp()/log(). Both stages are inexact because jax lowers exp2(z) ->
// exp(RN(z*RN(ln2))) -- reproduced bit-for-bit.
//
// R8 changes (numerics bit-identical, convoy/churn-targeted):
//  * R7 post-mortem: 64-VGPR hard cap likely forced spills (+5.7us); cap and
//    normal stores both reverted (back to R6's NT load + NT store config).
//  * Persistent resident grid: 1024 blocks x 256 thr (4 blocks/CU at ~100
//    VGPR -> 16 waves/CU, fully resident, zero block churn). Tables built
//    ONCE per block (4x fewer ocml table-exps than R6's 4096x512 one-shots).
//  * Iteration-boundary pipelining (R5's idea minus R5's mistake): loop body
//    is pack(cur) -> issue loads(next, SAME buffer; WAR-safe since pack's
//    reads issue first; sched_barrier stops the compiler from hoisting the
//    loads above pack and double-buffering into extra VGPR) -> decode/gelu/
//    encode(cur) -> store(cur). Next-tile loads have the whole ~2000-cy f64
//    chain to land -> pack's vmcnt wait ~0 in steady state, and every wave
//    keeps 8KB in flight DURING compute (R6's flat structure had 0 bytes in
//    flight for ~60% of each wave's period -> convoy bubbles).
//    NO mid-chain pack/loads (that was R5's regression: vmcnt wait + 12 DS
//    ops wedged between sigmoid and encode).
//  * Wave-local dataflow unchanged from R4/R6: value->lane map v = vwave +
//    (lane&7)*8 + (lane>>3); pack keeps own word (select i==lane&7); store
//    word via one __shfl from lane (lane&56)+i. No LDS data path, no loop
//    barriers.
//  * Encode shortcuts unchanged (absmax==0 five times):
//    - mantissa!=0 -> floor(log(a)/LN2) == E exactly (emu err ~1e-13 vs
//      1.7e-7 distance to integer); subnormal -> clip == -126; mantissa==0
//      (exact pow2) -> rare verbatim ocml log() path.
//    - mant = M + e, |e| <~ 1e-8: for sc > ctz(M), floor(mant*Lm[sc]) ==
//      M>>sc exactly -> parity is bit sc of M; only sc <= ctz(M) (incl. the
//      pow2 M=0 "W-1 garbage" case) runs the original f64 mul+floor step.

#define LN2C 0x1.62e42fefa39efp-1  // RN(ln2), XLA's folded log(2)

typedef unsigned int u32x4 __attribute__((ext_vector_type(4)));

__global__ __launch_bounds__(256) void spike_gelu_kernel(
    const u32x4* __restrict__ in, u32x4* __restrict__ out,
    int n_vals, int n_tiles) {
#pragma clang fp contract(off)
  const double LN2 = LN2C;
  // Tables (exact ocml-call replicas of the reference's constant arrays):
  __shared__ double Wdec[8];     // decode exponent weights exp2emu(7..0)
  __shared__ double Lms[23];     // ladder scales exp2emu(0..-22)
  __shared__ double E1t[256];    // ordered Wdec sum -> exp((e_c-127)*LN2)
  __shared__ double Vdec[23];    // decode fraction weights exp2emu(-1..-23)
  __shared__ double P2t[254];    // encode exp(-e0*LN2), e0 in [-126,127]
  __shared__ uint32_t etab[256]; // 8-step exponent floor-ladder per eb

  const int tid = threadIdx.x;
  const int lane = tid & 63;
  const int wid = tid >> 6;  // 0..3
  const int n_chunks = n_vals * 8;
  const int tstep = gridDim.x;  // grid-stride over 256-value tiles

  int tile = blockIdx.x;

  // ---- prologue: issue tile-0 loads (in flight under the table build) -----
  u32x4 A[8];
  {
    const int cb = tile * 2048 + wid * 512 + lane;
#pragma unroll
    for (int i = 0; i < 8; ++i) {
      int g = cb + i * 64;
      u32x4 b = {0u, 0u, 0u, 0u};
      if (g < n_chunks) b = __builtin_nontemporal_load(&in[g]);
      A[i] = b;
    }
  }

  // ---- table stage 1 ------------------------------------------------------
  if (tid < 8) Wdec[tid] = exp((double)(7 - tid) * LN2);
  if (tid >= 31 && tid < 54) Lms[tid - 31] = exp((double)(31 - tid) * LN2);
  __syncthreads();
  // ---- table stage 2 (reference op order) ---------------------------------
  if (tid == 0) {
    E1t[0] = exp(-126.0 * LN2);  // subnormal-branch scale (e_c==0)
  } else {
    double e_c = 0.0;
#pragma unroll
    for (int j = 0; j < 8; ++j)   // ascending-j einsum accumulation, verbatim
      if ((tid >> (7 - j)) & 1) e_c = e_c + Wdec[j];
    E1t[tid] = exp((e_c - 127.0) * LN2);
  }
  if (tid < 23) Vdec[tid] = exp((double)(-1 - tid) * LN2);
  if (tid < 254) P2t[tid] = exp((double)(126 - tid) * LN2);  // exp(-e0*LN2)
  if (tid >= 1 && tid < 255) {  // exponent-bit ladder, original formula
    double eb = (double)tid;
    uint32_t r = 0;
#pragma unroll
    for (int sc = 7; sc >= 0; --sc) {
      double f = floor(eb * Lms[sc]);
      double md = f - 2.0 * floor(0.5 * f);
      r |= ((uint32_t)md) << (23 + sc);
    }
    etab[tid] = r;
  } else {
    etab[tid] = 0u;  // hygiene, never read
  }
  __syncthreads();  // tables ready; no further block-wide coupling

  const int nibshift = 28 - 4 * (lane & 7);
  const int keep = lane & 7;

  // ---- steady-state resident loop (no barriers, no mid-chain memory) ------
  for (;;) {
    // pack(cur): wave-local bit transpose. Chunk cb+i*64 holds value
    // vwave+i*8+(lane>>3), nibble pos lane&7; after the 3 xor-ors lane keeps
    // its own value's word (v = vwave + (lane&7)*8 + (lane>>3)) at i==lane&7.
    uint32_t w0 = 0u;
#pragma unroll
    for (int i = 0; i < 8; ++i) {
      u32x4 b = A[i];
      uint32_t p = (((((b.x >> 23) & 1u) << 3) | (((b.y >> 23) & 1u) << 2) |
                     (((b.z >> 23) & 1u) << 1) | ((b.w >> 23) & 1u)))
                   << nibshift;
      p |= __shfl_xor(p, 1);
      p |= __shfl_xor(p, 2);
      p |= __shfl_xor(p, 4);
      if (keep == i) w0 = p;
    }
    // keep the compiler from hoisting next-tile loads above the pack (would
    // force a second 32-VGPR buffer and cross the 128-VGPR cliff)
    __builtin_amdgcn_sched_barrier(0);

    // issue loads(next) into the SAME buffer: WAR-safe (pack's reads issued
    // above); they have the entire f64 chain + store below to land.
    const int ntile = tile + tstep;
    const bool havenext = ntile < n_tiles;
    if (havenext) {
      const int cb = ntile * 2048 + wid * 512 + lane;
#pragma unroll
      for (int i = 0; i < 8; ++i) {
        int g = cb + i * 64;
        u32x4 b = {0u, 0u, 0u, 0u};
        if (g < n_chunks) b = __builtin_nontemporal_load(&in[g]);
        A[i] = b;
      }
    }

    // ---- per-value chain (bit-identical to R4/R6) -------------------------
    const int vwave = tile * 256 + wid * 64;
    const int v0 = vwave + (lane & 7) * 8 + (lane >> 3);
    const bool ok0 = v0 < n_vals;

    // DECODE
    double f0 = 0.0;
#pragma unroll
    for (int j = 0; j < 23; ++j)
      if ((w0 >> (22 - j)) & 1u) f0 = f0 + Vdec[j];
    uint32_t ei0 = (w0 >> 23) & 0xFFu;
    double sg0 = (w0 >> 31) ? -1.0 : 1.0;
    double fa0 = ei0 ? (1.0 + f0) : f0;
    double x0 = (sg0 * E1t[ei0]) * fa0;

    // f64 GELU, exp-form logistic, ocml exp
    double t0 = 1.702 * x0;
    double e0v = exp(-t0);
    double s0 = 1.0 / (1.0 + e0v);
    double y0 = x0 * s0;
    float yf0 = (float)y0;   // astype(float32): RN
    double yd0 = (double)yf0;

    // ENCODE
    double a0 = fabs(yd0);
    uint32_t yb0 = __float_as_uint(yf0);
    uint32_t Ef0 = (yb0 >> 23) & 0xFFu;
    uint32_t mbf0 = yb0 & 0x7FFFFFu;
    int e00 = (Ef0 == 0u) ? -126 : (int)Ef0 - 127;
    bool pw0 = ok0 && (a0 > 0.0) && (Ef0 != 0u) && (mbf0 == 0u);
    if (__builtin_expect(pw0, 0)) {  // exact pow2: ocml log boundary, verbatim
      double e0 = floor(log(a0) / LN2);
      e00 = (int)fmin(fmax(e0, -126.0), 127.0);
    }
    double p20 = P2t[e00 + 126];
    double m10 = a0 * p20;               // RN: may be W' +- eps
    double mant0 = (m10 - 1.0) * 8388608.0;  // Sterbenz-exact, exact scale
    int M0 = (int)rint(mant0);
    uint32_t mb0 = ((uint32_t)M0) & 0x7FFFFFu;
    int T0 = M0 ? __builtin_ctz((uint32_t)M0) : 23;
    int L0 = T0 < 22 ? T0 : 22;
    for (int sc = 0; sc <= L0; ++sc) {   // boundary scs: original f64 math
      double f = floor(mant0 * Lms[sc]);
      mb0 = (mb0 & ~(1u << sc)) | (((uint32_t)(((int)f) & 1)) << sc);
    }
    uint32_t ob0 = (yb0 & 0x80000000u) | etab[e00 + 127] | mb0;
    ob0 = (ok0 && a0 > 0.0) ? ob0 : 0u;

    // ---- store(cur): wave-local pulse expansion, NT -----------------------
    // Chunk cb+i*64 needs value vwave+i*8+(lane>>3), held at lane (lane&56)+i.
    uint32_t wv[8];
#pragma unroll
    for (int i = 0; i < 8; ++i) wv[i] = __shfl(ob0, (lane & 56) + i);
    const int cb = tile * 2048 + wid * 512 + lane;
    const int base = 31 - 4 * (lane & 7);
#pragma unroll
    for (int i = 0; i < 8; ++i) {
      int g = cb + i * 64;
      if (g < n_chunks) {
        uint32_t wa = wv[i];
        u32x4 o;
        o.x = ((wa >> base) & 1u) * 0x3F800000u;
        o.y = ((wa >> (base - 1)) & 1u) * 0x3F800000u;
        o.z = ((wa >> (base - 2)) & 1u) * 0x3F800000u;
        o.w = ((wa >> (base - 3)) & 1u) * 0x3F800000u;
        __builtin_nontemporal_store(o, &out[g]);
      }
    }

    if (!havenext) break;
    tile = ntile;
  }
}

extern "C" void kernel_launch(void* const* d_in, const int* in_sizes, int n_in,
                              void* d_out, int out_size, void* d_ws, size_t ws_size,
                              hipStream_t stream) {
  int n_vals = in_sizes[0] / 32;
  int n_tiles = (n_vals + 255) / 256;
  int grid = n_tiles < 1024 ? n_tiles : 1024;
  spike_gelu_kernel<<<grid, 256, 0, stream>>>(
      (const u32x4*)d_in[0], (u32x4*)d_out, n_vals, n_tiles);
}